// Round 1
// baseline (942.604 us; speedup 1.0000x reference)
//
#include <hip/hip_runtime.h>

#define EMBED 2048
#define HEADS 16
#define HDIM  128
#define BATCH 4
#define SEQ   2048
#define MROWS (BATCH*SEQ)   // 8192

typedef __attribute__((ext_vector_type(8))) _Float16 h8;
typedef __attribute__((ext_vector_type(4))) _Float16 h4;
typedef __attribute__((ext_vector_type(4))) float     f32x4;

__device__ inline f32x4 mfma16(h8 a, h8 b, f32x4 c){
  return __builtin_amdgcn_mfma_f32_16x16x32_f16(a, b, c, 0, 0, 0);
}

__device__ inline void gl_lds16(const void* g, void* l){
  __builtin_amdgcn_global_load_lds(
      (__attribute__((address_space(1))) unsigned*)g,
      (__attribute__((address_space(3))) unsigned*)l, 16, 0, 0);
}

// ---------------- fp32 -> fp16 convert ----------------
__global__ __launch_bounds__(256) void f2h_kernel(const float* __restrict__ src,
                                                  _Float16* __restrict__ dst, int n){
  int stride = gridDim.x * blockDim.x * 8;
  for (int i = (blockIdx.x*blockDim.x + threadIdx.x)*8; i < n; i += stride){
    f32x4 a = *(const f32x4*)(src + i);
    f32x4 b = *(const f32x4*)(src + i + 4);
    h8 o;
    o[0]=(_Float16)a[0]; o[1]=(_Float16)a[1]; o[2]=(_Float16)a[2]; o[3]=(_Float16)a[3];
    o[4]=(_Float16)b[0]; o[5]=(_Float16)b[1]; o[6]=(_Float16)b[2]; o[7]=(_Float16)b[3];
    *(h8*)(dst + i) = o;
  }
}

// ---------------- GEMM: C[M,N] = A[M,K] * Bw[N,K]^T + bias ----------------
// MODE 0: out f16 row-major [M][EMBED]         (Q, K projections)
// MODE 1: out f32 row-major [M][EMBED]         (final output)
// MODE 2: out f16 transposed [B,H,D,S]         (V projection -> V^T)
template<int MODE>
__global__ __launch_bounds__(256) void gemm_bt(const _Float16* __restrict__ A,
                                               const _Float16* __restrict__ Bw,
                                               const float* __restrict__ bias,
                                               void* __restrict__ Cout, int K)
{
  constexpr int BM=128, BN=128, BK=64;
  __shared__ _Float16 Al[BM*BK];
  __shared__ _Float16 Bl[BN*BK];
  const int tid = threadIdx.x;
  const int l = tid & 63, w = tid >> 6;
  const int bm = blockIdx.x * BM, bn = blockIdx.y * BN;
  const int wm = (w & 1) * 64, wn = (w >> 1) * 64;
  const f32x4 zero = {0.f,0.f,0.f,0.f};
  f32x4 acc[4][4];
  #pragma unroll
  for (int mi=0;mi<4;++mi)
    #pragma unroll
    for (int ni=0;ni<4;++ni) acc[mi][ni]=zero;

  for (int kt = 0; kt < K; kt += BK){
    __syncthreads();
    #pragma unroll
    for (int i=0;i<4;++i){
      int row = w*32 + i*8 + (l>>3);
      int col = (l&7)*8;
      gl_lds16(A  + (size_t)(bm+row)*K + kt + col, &Al[(w*32 + i*8)*BK]);
      gl_lds16(Bw + (size_t)(bn+row)*K + kt + col, &Bl[(w*32 + i*8)*BK]);
    }
    __syncthreads();
    #pragma unroll
    for (int ks=0; ks<BK; ks+=32){
      h8 af[4], bf[4];
      #pragma unroll
      for (int mi=0;mi<4;++mi) af[mi] = *(const h8*)&Al[(wm + mi*16 + (l&15))*BK + ks + ((l>>4)*8)];
      #pragma unroll
      for (int ni=0;ni<4;++ni) bf[ni] = *(const h8*)&Bl[(wn + ni*16 + (l&15))*BK + ks + ((l>>4)*8)];
      #pragma unroll
      for (int mi=0;mi<4;++mi)
        #pragma unroll
        for (int ni=0;ni<4;++ni)
          acc[mi][ni] = mfma16(af[mi], bf[ni], acc[mi][ni]);
    }
  }

  #pragma unroll
  for (int ni=0;ni<4;++ni){
    int n = bn + wn + ni*16 + (l & 15);
    float bv = bias[n];
    #pragma unroll
    for (int mi=0;mi<4;++mi){
      int m0 = bm + wm + mi*16 + ((l>>4)*4);
      if constexpr (MODE==0){
        #pragma unroll
        for (int r=0;r<4;++r)
          ((_Float16*)Cout)[(size_t)(m0+r)*EMBED + n] = (_Float16)(acc[mi][ni][r] + bv);
      } else if constexpr (MODE==1){
        #pragma unroll
        for (int r=0;r<4;++r)
          ((float*)Cout)[(size_t)(m0+r)*EMBED + n] = acc[mi][ni][r] + bv;
      } else {
        int b = m0 >> 11, s0 = m0 & (SEQ-1);
        int hh = n >> 7,  d  = n & (HDIM-1);
        h4 pk;
        #pragma unroll
        for (int r=0;r<4;++r) pk[r] = (_Float16)(acc[mi][ni][r] + bv);
        *(h4*)((_Float16*)Cout + ((size_t)(b*HEADS + hh)*HDIM + d)*SEQ + s0) = pk;
      }
    }
  }
}

// ---------------- Flash attention with ALiBi ----------------
// Q,K: f16 [B,S,EMBED] (col = h*128+d). V: f16 [B,H,D,S]. Out: f16 [B,S,EMBED].
__global__ __launch_bounds__(256) void attn_kernel(const _Float16* __restrict__ Q,
                                                   const _Float16* __restrict__ Kt,
                                                   const _Float16* __restrict__ Vt_g,
                                                   _Float16* __restrict__ O)
{
  constexpr int QB=64, KB=64;
  __shared__ _Float16 Kl[KB][HDIM+8];
  __shared__ _Float16 Vl[HDIM][KB+8];
  __shared__ _Float16 Pl[4][16][KB+8];
  const int tid = threadIdx.x, l = tid & 63, w = tid >> 6;
  const int bh = blockIdx.y;
  const int b = bh >> 4, h = bh & 15;
  const int q0 = blockIdx.x * QB;
  const float slope = exp2f((float)h - 8.0f);   // |s-t| * 2^(h-8), positive (faithful to ref)
  const float scale = 0.08838834764831845f;     // 1/sqrt(128)
  const f32x4 zero = {0.f,0.f,0.f,0.f};

  h8 qf[4];
  {
    int qrow = q0 + w*16 + (l & 15);
    const _Float16* qp = Q + (size_t)(b*SEQ + qrow)*EMBED + h*HDIM + ((l>>4)*8);
    #pragma unroll
    for (int ks=0;ks<4;++ks) qf[ks] = *(const h8*)(qp + ks*32);
  }
  float mrow[4], lsum[4];
  f32x4 acc[8];
  #pragma unroll
  for (int df=0;df<8;++df) acc[df]=zero;
  #pragma unroll
  for (int r=0;r<4;++r){ mrow[r] = -3.0e38f; lsum[r] = 0.f; }

  const int sr = tid >> 2;         // K stage: row 0..63
  const int sd = (tid & 3) * 32;   //          d segment
  const int vdr = tid >> 1;        // V stage: d row 0..127
  const int vss = (tid & 1) * 32;  //          s segment

  for (int kt = 0; kt < SEQ; kt += KB){
    __syncthreads();
    {
      const _Float16* gk = Kt + (size_t)(b*SEQ + kt + sr)*EMBED + h*HDIM + sd;
      h8 k0 = ((const h8*)gk)[0], k1 = ((const h8*)gk)[1],
         k2 = ((const h8*)gk)[2], k3 = ((const h8*)gk)[3];
      *(h8*)&Kl[sr][sd]    = k0;  *(h8*)&Kl[sr][sd+8]  = k1;
      *(h8*)&Kl[sr][sd+16] = k2;  *(h8*)&Kl[sr][sd+24] = k3;
      const _Float16* gv = Vt_g + ((size_t)bh*HDIM + vdr)*SEQ + kt + vss;
      h8 v0 = ((const h8*)gv)[0], v1 = ((const h8*)gv)[1],
         v2 = ((const h8*)gv)[2], v3 = ((const h8*)gv)[3];
      *(h8*)&Vl[vdr][vss]    = v0;  *(h8*)&Vl[vdr][vss+8]  = v1;
      *(h8*)&Vl[vdr][vss+16] = v2;  *(h8*)&Vl[vdr][vss+24] = v3;
    }
    __syncthreads();

    float p[4][4];
    #pragma unroll
    for (int nf=0;nf<4;++nf){
      f32x4 s = zero;
      #pragma unroll
      for (int ks=0;ks<4;++ks){
        h8 kf = *(const h8*)&Kl[nf*16 + (l&15)][ks*32 + ((l>>4)*8)];
        s = mfma16(qf[ks], kf, s);
      }
      int tcol = kt + nf*16 + (l & 15);
      #pragma unroll
      for (int r=0;r<4;++r){
        int qr = q0 + w*16 + ((l>>4)*4) + r;
        p[nf][r] = s[r]*scale + slope*fabsf((float)(qr - tcol));
      }
    }
    float pm[4];
    #pragma unroll
    for (int r=0;r<4;++r)
      pm[r] = fmaxf(fmaxf(p[0][r],p[1][r]), fmaxf(p[2][r],p[3][r]));
    #pragma unroll
    for (int off=1; off<16; off<<=1){
      #pragma unroll
      for (int r=0;r<4;++r) pm[r] = fmaxf(pm[r], __shfl_xor(pm[r], off));
    }
    float rs[4];
    #pragma unroll
    for (int r=0;r<4;++r){
      float mn = fmaxf(mrow[r], pm[r]);
      float sc = __expf(mrow[r] - mn);
      mrow[r] = mn;
      lsum[r] *= sc;
      rs[r] = 0.f;
      #pragma unroll
      for (int nf=0;nf<4;++nf){
        p[nf][r] = __expf(p[nf][r] - mn);
        rs[r] += p[nf][r];
      }
      #pragma unroll
      for (int df=0;df<8;++df) acc[df][r] *= sc;
    }
    #pragma unroll
    for (int off=1; off<16; off<<=1){
      #pragma unroll
      for (int r=0;r<4;++r) rs[r] += __shfl_xor(rs[r], off);
    }
    #pragma unroll
    for (int r=0;r<4;++r) lsum[r] += rs[r];

    #pragma unroll
    for (int nf=0;nf<4;++nf)
      #pragma unroll
      for (int r=0;r<4;++r)
        Pl[w][((l>>4)*4)+r][nf*16 + (l&15)] = (_Float16)p[nf][r];
    // same-wave LDS write->read: in-order, no barrier needed
    #pragma unroll
    for (int ks=0; ks<2; ++ks){
      h8 pf = *(const h8*)&Pl[w][l & 15][ks*32 + ((l>>4)*8)];
      #pragma unroll
      for (int df=0; df<8; ++df){
        h8 vf = *(const h8*)&Vl[df*16 + (l&15)][ks*32 + ((l>>4)*8)];
        acc[df] = mfma16(pf, vf, acc[df]);
      }
    }
  }
  #pragma unroll
  for (int df=0; df<8; ++df){
    int d = df*16 + (l & 15);
    #pragma unroll
    for (int r=0;r<4;++r){
      int s = q0 + w*16 + ((l>>4)*4) + r;
      float v = acc[df][r] / lsum[r];
      O[(size_t)(b*SEQ + s)*EMBED + h*HDIM + d] = (_Float16)v;
    }
  }
}

extern "C" void kernel_launch(void* const* d_in, const int* in_sizes, int n_in,
                              void* d_out, int out_size, void* d_ws, size_t ws_size,
                              hipStream_t stream)
{
  const float* x   = (const float*)d_in[0];
  const float* q_w = (const float*)d_in[1];
  const float* q_b = (const float*)d_in[2];
  const float* k_w = (const float*)d_in[3];
  const float* k_b = (const float*)d_in[4];
  const float* v_w = (const float*)d_in[5];
  const float* v_b = (const float*)d_in[6];
  const float* o_w = (const float*)d_in[7];
  const float* o_b = (const float*)d_in[8];

  char* ws = (char*)d_ws;
  _Float16* xh = (_Float16*)(ws);                    // 33,554,432 B
  _Float16* wq = (_Float16*)(ws + 33554432);         //  8,388,608 B
  _Float16* wk = (_Float16*)(ws + 41943040);
  _Float16* wv = (_Float16*)(ws + 50331648);
  _Float16* wo = (_Float16*)(ws + 58720256);
  _Float16* Qf = (_Float16*)(ws + 67108864);         // [M][E] f16
  _Float16* Kf = (_Float16*)(ws + 100663296);        // [M][E] f16
  _Float16* Vt = (_Float16*)(ws + 134217728);        // [B,H,D,S] f16
  _Float16* Ah = xh;                                 // attn out reuses xh region

  f2h_kernel<<<1024, 256, 0, stream>>>(x,   xh, MROWS*EMBED);
  f2h_kernel<<<512,  256, 0, stream>>>(q_w, wq, EMBED*EMBED);
  f2h_kernel<<<512,  256, 0, stream>>>(k_w, wk, EMBED*EMBED);
  f2h_kernel<<<512,  256, 0, stream>>>(v_w, wv, EMBED*EMBED);
  f2h_kernel<<<512,  256, 0, stream>>>(o_w, wo, EMBED*EMBED);

  dim3 gg(MROWS/128, EMBED/128);
  gemm_bt<0><<<gg, 256, 0, stream>>>(xh, wq, q_b, (void*)Qf, EMBED);
  gemm_bt<0><<<gg, 256, 0, stream>>>(xh, wk, k_b, (void*)Kf, EMBED);
  gemm_bt<2><<<gg, 256, 0, stream>>>(xh, wv, v_b, (void*)Vt, EMBED);

  dim3 ga(SEQ/64, BATCH*HEADS);
  attn_kernel<<<ga, 256, 0, stream>>>(Qf, Kf, Vt, Ah);

  gemm_bt<1><<<gg, 256, 0, stream>>>(Ah, wo, o_b, d_out, EMBED);
}

// Round 3
// 781.323 us; speedup vs baseline: 1.2064x; 1.2064x over previous
//
#include <hip/hip_runtime.h>

#define EMBED 2048
#define HEADS 16
#define HDIM  128
#define BATCH 4
#define SEQ   2048
#define MROWS (BATCH*SEQ)   // 8192

typedef __attribute__((ext_vector_type(8)))  _Float16 h8;
typedef __attribute__((ext_vector_type(4)))  _Float16 h4;
typedef __attribute__((ext_vector_type(4)))  float    f32x4;
typedef __attribute__((ext_vector_type(16))) float    f32x16;
typedef __attribute__((ext_vector_type(4)))  unsigned u32x4;

__device__ inline f32x4 mfma16(h8 a, h8 b, f32x4 c){
  return __builtin_amdgcn_mfma_f32_16x16x32_f16(a, b, c, 0, 0, 0);
}
__device__ inline f32x16 mfma32(h8 a, h8 b, f32x16 c){
  return __builtin_amdgcn_mfma_f32_32x32x16_f16(a, b, c, 0, 0, 0);
}
__device__ inline unsigned pkrtz(float a, float b){
  auto t = __builtin_amdgcn_cvt_pkrtz(a, b);   // 2 x f16, RTZ
  return __builtin_bit_cast(unsigned, t);
}
__device__ inline void gl_lds16(const void* g, void* l){
  __builtin_amdgcn_global_load_lds(
      (__attribute__((address_space(1))) unsigned*)g,
      (__attribute__((address_space(3))) unsigned*)l, 16, 0, 0);
}

// ---------------- fp32 -> fp16 convert ----------------
__global__ __launch_bounds__(256) void f2h_kernel(const float* __restrict__ src,
                                                  _Float16* __restrict__ dst, int n){
  int stride = gridDim.x * blockDim.x * 8;
  for (int i = (blockIdx.x*blockDim.x + threadIdx.x)*8; i < n; i += stride){
    f32x4 a = *(const f32x4*)(src + i);
    f32x4 b = *(const f32x4*)(src + i + 4);
    h8 o;
    o[0]=(_Float16)a[0]; o[1]=(_Float16)a[1]; o[2]=(_Float16)a[2]; o[3]=(_Float16)a[3];
    o[4]=(_Float16)b[0]; o[5]=(_Float16)b[1]; o[6]=(_Float16)b[2]; o[7]=(_Float16)b[3];
    *(h8*)(dst + i) = o;
  }
}

// ---------------- GEMM: C[M,N] = A[M,K] * Bw[N,K]^T + bias ----------------
template<int MODE>
__global__ __launch_bounds__(256) void gemm_bt(const _Float16* __restrict__ A,
                                               const _Float16* __restrict__ Bw,
                                               const float* __restrict__ bias,
                                               void* __restrict__ Cout, int K)
{
  constexpr int BM=128, BN=128, BK=64;
  __shared__ __align__(16) _Float16 Al[BM*BK];
  __shared__ __align__(16) _Float16 Bl[BN*BK];
  const int tid = threadIdx.x;
  const int l = tid & 63, w = tid >> 6;
  const int bm = blockIdx.x * BM, bn = blockIdx.y * BN;
  const int wm = (w & 1) * 64, wn = (w >> 1) * 64;
  const f32x4 zero = {0.f,0.f,0.f,0.f};
  f32x4 acc[4][4];
  #pragma unroll
  for (int mi=0;mi<4;++mi)
    #pragma unroll
    for (int ni=0;ni<4;++ni) acc[mi][ni]=zero;

  for (int kt = 0; kt < K; kt += BK){
    __syncthreads();
    #pragma unroll
    for (int i=0;i<4;++i){
      int row = w*32 + i*8 + (l>>3);
      int col = (l&7)*8;
      gl_lds16(A  + (size_t)(bm+row)*K + kt + col, &Al[(w*32 + i*8)*BK]);
      gl_lds16(Bw + (size_t)(bn+row)*K + kt + col, &Bl[(w*32 + i*8)*BK]);
    }
    __syncthreads();
    #pragma unroll
    for (int ks=0; ks<BK; ks+=32){
      h8 af[4], bf[4];
      #pragma unroll
      for (int mi=0;mi<4;++mi) af[mi] = *(const h8*)&Al[(wm + mi*16 + (l&15))*BK + ks + ((l>>4)*8)];
      #pragma unroll
      for (int ni=0;ni<4;++ni) bf[ni] = *(const h8*)&Bl[(wn + ni*16 + (l&15))*BK + ks + ((l>>4)*8)];
      #pragma unroll
      for (int mi=0;mi<4;++mi)
        #pragma unroll
        for (int ni=0;ni<4;++ni)
          acc[mi][ni] = mfma16(af[mi], bf[ni], acc[mi][ni]);
    }
  }

  #pragma unroll
  for (int ni=0;ni<4;++ni){
    int n = bn + wn + ni*16 + (l & 15);
    float bv = bias[n];
    #pragma unroll
    for (int mi=0;mi<4;++mi){
      int m0 = bm + wm + mi*16 + ((l>>4)*4);
      if constexpr (MODE==0){
        #pragma unroll
        for (int r=0;r<4;++r)
          ((_Float16*)Cout)[(size_t)(m0+r)*EMBED + n] = (_Float16)(acc[mi][ni][r] + bv);
      } else if constexpr (MODE==1){
        #pragma unroll
        for (int r=0;r<4;++r)
          ((float*)Cout)[(size_t)(m0+r)*EMBED + n] = acc[mi][ni][r] + bv;
      } else {
        int b = m0 >> 11, s0 = m0 & (SEQ-1);
        int hh = n >> 7,  d  = n & (HDIM-1);
        h4 pk;
        #pragma unroll
        for (int r=0;r<4;++r) pk[r] = (_Float16)(acc[mi][ni][r] + bv);
        *(h4*)((_Float16*)Cout + ((size_t)(b*HEADS + hh)*HDIM + d)*SEQ + s0) = pk;
      }
    }
  }
}

// ---------------- Flash attention, 8-wave 32x32 swapped-operand ----------------
// Q,K: f16 [B,S,EMBED]; V: f16 [B,H,D,S]; Out: f16 [B,S,EMBED].
// Per wave: 32 q-rows. QK^T swapped (A=K,B=Q) -> C[col=q][row=t]: softmax lane-local.
// PV: A=P built in-register (cvt_pkrtz + shfl_xor(32) half-wave exchange), B=V.
__global__ __launch_bounds__(512, 2) void attn_kernel(const _Float16* __restrict__ Qf,
                                                      const _Float16* __restrict__ Kf,
                                                      const _Float16* __restrict__ Vt,
                                                      _Float16* __restrict__ O)
{
  __shared__ __align__(16) _Float16 Kl[64*128];   // K-tile [t=64][d=128], XOR-swizzled
  __shared__ __align__(16) _Float16 Vl[128*64];   // V^T-tile [d=128][t=64], XOR-swizzled
  char* klb = (char*)Kl; char* vlb = (char*)Vl;

  const int tid = threadIdx.x;
  const int l = tid & 63, w = tid >> 6;
  const int l31 = l & 31, hi = l >> 5;
  // XCD-chunked swizzle: all 8 q-tiles of a bh group land on one XCD (L2 reuse)
  const int bid = blockIdx.x;
  const int swz = (bid & 7)*64 + (bid >> 3);
  const int bh = swz >> 3, qt = swz & 7;
  const int b = bh >> 4, h = bh & 15;
  const int q0w = qt*256 + w*32;

  const float slope2 = exp2f((float)(h - 8)) * 1.44269504f;  // ALiBi slope in log2-units
  const float scale2 = 0.08838834764831845f * 1.44269504f;   // 1/sqrt(128) * log2(e)

  // Q fragments (B-operand): lane holds Q[q0w+l31][d = ks*16 + hi*8 + j]
  h8 qfr[8];
  {
    const _Float16* qp = Qf + ((size_t)(b*SEQ) + q0w + l31)*EMBED + h*HDIM + hi*8;
    #pragma unroll
    for (int ks=0;ks<8;++ks) qfr[ks] = *(const h8*)(qp + ks*16);
  }

  f32x16 acc[4];
  #pragma unroll
  for (int d=0; d<4; ++d)
    #pragma unroll
    for (int i=0; i<16; ++i) acc[d][i] = 0.f;
  float m = -1e9f, lsum = 0.f;

  // staging: K: thread -> row tid>>3, 32B at col (tid&7)*16; V: row tid>>2, 32B at (tid&3)*16
  const int krow = tid >> 3, kcol = tid & 7;
  const int vrow = tid >> 2, vcol = tid & 3;
  const _Float16* kg = Kf + ((size_t)(b*SEQ) + krow)*EMBED + h*HDIM + kcol*16;
  const _Float16* vg = Vt + ((size_t)bh*HDIM + vrow)*SEQ + vcol*16;
  const unsigned kb0 = (unsigned)(krow*256 + kcol*32)      ^ ((krow&7)<<4);
  const unsigned kb1 = (unsigned)(krow*256 + kcol*32 + 16) ^ ((krow&7)<<4);
  const unsigned vb0 = (unsigned)(vrow*128 + vcol*32)      ^ ((vrow&7)<<4);
  const unsigned vb1 = (unsigned)(vrow*128 + vcol*32 + 16) ^ ((vrow&7)<<4);

  const float qv = (float)(q0w + l31);
  const int sw7 = (l & 7) << 4;   // read-side swizzle (row&7 == l&7 for all frag reads)

  for (int kt = 0; kt < SEQ; kt += 64){
    __syncthreads();
    {
      h8 a0 = *(const h8*)(kg); h8 a1 = *(const h8*)(kg + 8);
      h8 c0 = *(const h8*)(vg); h8 c1 = *(const h8*)(vg + 8);
      *(h8*)(klb + kb0) = a0; *(h8*)(klb + kb1) = a1;
      *(h8*)(vlb + vb0) = c0; *(h8*)(vlb + vb1) = c1;
      kg += (size_t)64*EMBED; vg += 64;
    }
    __syncthreads();

    // ---- QK^T (swapped): C[col=q=l31][row=t] ----
    f32x16 s0, s1;
    #pragma unroll
    for (int i=0;i<16;++i){ s0[i]=0.f; s1[i]=0.f; }
    #pragma unroll
    for (int ks=0;ks<8;++ks){
      int colb = ks*32 + hi*16;
      h8 k0 = *(const h8*)(klb + (((l31     )*256 + colb) ^ sw7));
      h8 k1 = *(const h8*)(klb + (((l31 + 32)*256 + colb) ^ sw7));
      s0 = mfma32(k0, qfr[ks], s0);
      s1 = mfma32(k1, qfr[ks], s1);
    }

    // ---- ALiBi bias + row max (lane-local) ----
    float a0r[16], a1r[16];
    float pm = -1e9f;
    const float tb = (float)kt;
    #pragma unroll
    for (int i=0;i<16;++i){
      float pat = (float)((i&3) + 8*(i>>2) + hi*4);
      float t0 = tb + pat, t1 = tb + 32.f + pat;
      a0r[i] = fmaf(slope2, fabsf(qv - t0), s0[i]*scale2);
      a1r[i] = fmaf(slope2, fabsf(qv - t1), s1[i]*scale2);
      pm = fmaxf(pm, fmaxf(a0r[i], a1r[i]));
    }
    pm = fmaxf(pm, __shfl_xor(pm, 32));

    // ---- defer-max rescale (T13) ----
    if (__any(pm > m + 11.f)){
      float mn = fmaxf(m, pm);
      float sc = exp2f(m - mn);
      m = mn; lsum *= sc;
      #pragma unroll
      for (int i=0;i<16;++i){
        float scv = __shfl(sc, (i&3) + 8*(i>>2) + hi*4);
        #pragma unroll
        for (int d=0;d<4;++d) acc[d][i] *= scv;
      }
    }

    // ---- exp2 + row sum ----
    float p0[16], p1[16];
    float rs = 0.f;
    #pragma unroll
    for (int i=0;i<16;++i){
      p0[i] = exp2f(a0r[i] - m);
      p1[i] = exp2f(a1r[i] - m);
      rs += p0[i] + p1[i];
    }
    lsum += rs + __shfl_xor(rs, 32);

    // ---- P -> f16 A-operand fragments: cvt_pkrtz + half-wave shfl_xor exchange ----
    // Lane (q=l31, hi) holds t = ks*16 + (i&3) + 8*(i>>2) + 4*hi. A-frag j -> t = ks*16 + hi*8 + j.
    unsigned paw[4][4];
    {
      auto buildP = [&](const float (&p)[16], int tt){
        #pragma unroll
        for (int hf=0; hf<2; ++hf){
          const int E = hf*8;
          unsigned A0 = pkrtz(p[E+0], p[E+1]), A1 = pkrtz(p[E+2], p[E+3]);
          unsigned B0 = pkrtz(p[E+4], p[E+5]), B1 = pkrtz(p[E+6], p[E+7]);
          unsigned sA0 = __shfl_xor(A0, 32), sA1 = __shfl_xor(A1, 32);
          unsigned sB0 = __shfl_xor(B0, 32), sB1 = __shfl_xor(B1, 32);
          const int ks = tt*2 + hf;
          paw[ks][0] = hi ? sB0 : A0;   // j=0,1
          paw[ks][1] = hi ? sB1 : A1;   // j=2,3
          paw[ks][2] = hi ? B0  : sA0;  // j=4,5
          paw[ks][3] = hi ? B1  : sA1;  // j=6,7
        }
      };
      buildP(p0, 0);
      buildP(p1, 1);
    }

    // ---- PV: acc[dblk] = C[col=d][row=q] ----
    #pragma unroll
    for (int ks=0; ks<4; ++ks){
      u32x4 pw = {paw[ks][0], paw[ks][1], paw[ks][2], paw[ks][3]};
      h8 pa = __builtin_bit_cast(h8, pw);
      #pragma unroll
      for (int d=0; d<4; ++d){
        h8 vf = *(const h8*)(vlb + (((d*32 + l31)*128 + ks*32 + hi*16) ^ sw7));
        acc[d] = mfma32(pa, vf, acc[d]);
      }
    }
  }

  // ---- epilogue: divide by lsum (broadcast per C-row), scalar f16 stores ----
  float inv = 1.0f / lsum;
  _Float16* ob = O + ((size_t)(b*SEQ) + q0w)*EMBED + h*HDIM + l31;
  #pragma unroll
  for (int i=0;i<16;++i){
    int ql = (i&3) + 8*(i>>2) + hi*4;
    float iq = __shfl(inv, ql);
    #pragma unroll
    for (int d=0;d<4;++d)
      ob[(size_t)ql*EMBED + d*32] = (_Float16)(acc[d][i] * iq);
  }
}

extern "C" void kernel_launch(void* const* d_in, const int* in_sizes, int n_in,
                              void* d_out, int out_size, void* d_ws, size_t ws_size,
                              hipStream_t stream)
{
  const float* x   = (const float*)d_in[0];
  const float* q_w = (const float*)d_in[1];
  const float* q_b = (const float*)d_in[2];
  const float* k_w = (const float*)d_in[3];
  const float* k_b = (const float*)d_in[4];
  const float* v_w = (const float*)d_in[5];
  const float* v_b = (const float*)d_in[6];
  const float* o_w = (const float*)d_in[7];
  const float* o_b = (const float*)d_in[8];

  char* ws = (char*)d_ws;
  _Float16* xh = (_Float16*)(ws);                    // 33,554,432 B
  _Float16* wq = (_Float16*)(ws + 33554432);
  _Float16* wk = (_Float16*)(ws + 41943040);
  _Float16* wv = (_Float16*)(ws + 50331648);
  _Float16* wo = (_Float16*)(ws + 58720256);
  _Float16* Qf = (_Float16*)(ws + 67108864);         // [M][E] f16
  _Float16* Kf = (_Float16*)(ws + 100663296);        // [M][E] f16
  _Float16* Vt = (_Float16*)(ws + 134217728);        // [B,H,D,S] f16
  _Float16* Ah = xh;                                 // attn out reuses xh region

  f2h_kernel<<<1024, 256, 0, stream>>>(x,   xh, MROWS*EMBED);
  f2h_kernel<<<512,  256, 0, stream>>>(q_w, wq, EMBED*EMBED);
  f2h_kernel<<<512,  256, 0, stream>>>(k_w, wk, EMBED*EMBED);
  f2h_kernel<<<512,  256, 0, stream>>>(v_w, wv, EMBED*EMBED);
  f2h_kernel<<<512,  256, 0, stream>>>(o_w, wo, EMBED*EMBED);

  dim3 gg(MROWS/128, EMBED/128);
  gemm_bt<0><<<gg, 256, 0, stream>>>(xh, wq, q_b, (void*)Qf, EMBED);
  gemm_bt<0><<<gg, 256, 0, stream>>>(xh, wk, k_b, (void*)Kf, EMBED);
  gemm_bt<2><<<gg, 256, 0, stream>>>(xh, wv, v_b, (void*)Vt, EMBED);

  attn_kernel<<<512, 512, 0, stream>>>(Qf, Kf, Vt, Ah);

  gemm_bt<1><<<gg, 256, 0, stream>>>(Ah, wo, o_b, d_out, EMBED);
}